// Round 1
// baseline (603.542 us; speedup 1.0000x reference)
//
#include <hip/hip_runtime.h>
#include <hip/hip_bf16.h>

#define SEQ  2048
#define DH   64
#define QBLK 64          // q rows per block = 4 waves x 16
#define KBLK 32          // k/v rows per inner iteration

typedef short bf16x8 __attribute__((ext_vector_type(8)));   // 8 bf16 (bits) = 4 VGPRs
typedef float f32x4  __attribute__((ext_vector_type(4)));

// fp32 -> bf16 bits, round-to-nearest-even
__device__ __forceinline__ short bfbits(float f) {
    unsigned int u = __float_as_uint(f);
    u += 0x7fff + ((u >> 16) & 1);
    return (short)(u >> 16);
}

// load 8 consecutive fp32, scale, convert to bf16x8 fragment
__device__ __forceinline__ bf16x8 load8(const float* p, float scale) {
    const float4 a = *reinterpret_cast<const float4*>(p);
    const float4 b = *reinterpret_cast<const float4*>(p + 4);
    bf16x8 r;
    r[0] = bfbits(a.x * scale); r[1] = bfbits(a.y * scale);
    r[2] = bfbits(a.z * scale); r[3] = bfbits(a.w * scale);
    r[4] = bfbits(b.x * scale); r[5] = bfbits(b.y * scale);
    r[6] = bfbits(b.z * scale); r[7] = bfbits(b.w * scale);
    return r;
}

__global__ __launch_bounds__(256) void attn_fwd(const float* __restrict__ Qg,
                                                const float* __restrict__ Kg,
                                                const float* __restrict__ Vg,
                                                float* __restrict__ Og) {
    // per-wave private P tile, [16 rows][32 cols] bf16, padded 40 to spread banks
    __shared__ __align__(16) short P_lds[4][16][40];

    const int tid  = threadIdx.x;
    const int w    = tid >> 6;       // wave 0..3
    const int lane = tid & 63;
    const int lg   = lane >> 4;      // 16-lane group 0..3
    const int lr   = lane & 15;

    const int qblk = blockIdx.x & ((SEQ / QBLK) - 1);
    const int bh   = blockIdx.x / (SEQ / QBLK);
    const int q0   = qblk * QBLK;

    const float* Qb = Qg + (size_t)bh * SEQ * DH;
    const float* Kb = Kg + (size_t)bh * SEQ * DH;
    const float* Vb = Vg + (size_t)bh * SEQ * DH;
    float*       Ob = Og + (size_t)bh * SEQ * DH;

    // ---- Q fragments (A operand): row = lane&15, k-chunk = (lane>>4)*8 ----
    // scale by 1/sqrt(64) = 0.125 folded into Q (exact in fp32)
    const int qrow_frag = q0 + w * 16 + lr;
    bf16x8 qf[2];
    #pragma unroll
    for (int c = 0; c < 2; ++c)
        qf[c] = load8(Qb + (size_t)qrow_frag * DH + c * 32 + lg * 8, 0.125f);

    f32x4 o[4];
    #pragma unroll
    for (int dt = 0; dt < 4; ++dt) o[dt] = (f32x4){0.f, 0.f, 0.f, 0.f};
    float m_r[4], l_r[4];
    #pragma unroll
    for (int r = 0; r < 4; ++r) { m_r[r] = -1e30f; l_r[r] = 0.f; }

    const int kend = q0 + w * 16 + 16;   // causal limit for this wave's rows

    for (int kb = 0; kb < kend; kb += KBLK) {
        // K fragments (B operand, K stored [k][d] == B^T convention):
        // col = lane&15 (k within 16-tile), reduction chunk = (lane>>4)*8 (d)
        bf16x8 kf[2][2];
        #pragma unroll
        for (int t = 0; t < 2; ++t)
            #pragma unroll
            for (int c = 0; c < 2; ++c)
                kf[t][c] = load8(Kb + (size_t)(kb + t * 16 + lr) * DH + c * 32 + lg * 8, 1.0f);

        // V fragments (B operand, V stored [k][d], NOT transposed):
        // element = V[kb + (lane>>4)*8 + j][dt*16 + lane&15]
        bf16x8 vf[4];
        #pragma unroll
        for (int dt = 0; dt < 4; ++dt)
            #pragma unroll
            for (int j = 0; j < 8; ++j)
                vf[dt][j] = bfbits(Vb[(size_t)(kb + lg * 8 + j) * DH + dt * 16 + lr]);

        // ---- S = Q K^T (scaled) : two 16x16 column tiles ----
        f32x4 s[2];
        s[0] = (f32x4){0.f, 0.f, 0.f, 0.f};
        s[1] = (f32x4){0.f, 0.f, 0.f, 0.f};
        s[0] = __builtin_amdgcn_mfma_f32_16x16x32_bf16(qf[0], kf[0][0], s[0], 0, 0, 0);
        s[0] = __builtin_amdgcn_mfma_f32_16x16x32_bf16(qf[1], kf[0][1], s[0], 0, 0, 0);
        s[1] = __builtin_amdgcn_mfma_f32_16x16x32_bf16(qf[0], kf[1][0], s[1], 0, 0, 0);
        s[1] = __builtin_amdgcn_mfma_f32_16x16x32_bf16(qf[1], kf[1][1], s[1], 0, 0, 0);

        // ---- causal mask + per-row max (C/D: row=(lane>>4)*4+r, col=lane&15) ----
        float mx[4];
        #pragma unroll
        for (int r = 0; r < 4; ++r) {
            const int qg = q0 + w * 16 + lg * 4 + r;
            if (kb + lr > qg)      s[0][r] = -1e30f;
            if (kb + 16 + lr > qg) s[1][r] = -1e30f;
            mx[r] = fmaxf(s[0][r], s[1][r]);
        }
        #pragma unroll
        for (int d = 1; d < 16; d <<= 1)
            #pragma unroll
            for (int r = 0; r < 4; ++r)
                mx[r] = fmaxf(mx[r], __shfl_xor(mx[r], d));

        // ---- online softmax update ----
        float p0[4], p1[4], scl[4], sm[4];
        #pragma unroll
        for (int r = 0; r < 4; ++r) {
            const float mn = fmaxf(m_r[r], mx[r]);
            scl[r] = __expf(m_r[r] - mn);
            m_r[r] = mn;
            p0[r]  = __expf(s[0][r] - mn);
            p1[r]  = __expf(s[1][r] - mn);
            sm[r]  = p0[r] + p1[r];
        }
        #pragma unroll
        for (int d = 1; d < 16; d <<= 1)
            #pragma unroll
            for (int r = 0; r < 4; ++r)
                sm[r] += __shfl_xor(sm[r], d);
        #pragma unroll
        for (int r = 0; r < 4; ++r)
            l_r[r] = l_r[r] * scl[r] + sm[r];
        #pragma unroll
        for (int dt = 0; dt < 4; ++dt)
            #pragma unroll
            for (int r = 0; r < 4; ++r)
                o[dt][r] *= scl[r];

        // ---- P: D-layout -> LDS -> A-layout fragment ----
        #pragma unroll
        for (int r = 0; r < 4; ++r) {
            const int row = lg * 4 + r;
            P_lds[w][row][lr]      = bfbits(p0[r]);
            P_lds[w][row][16 + lr] = bfbits(p1[r]);
        }
        // wave-private tile: in-order LDS + compiler lgkmcnt handles RAW, no barrier
        const bf16x8 pa = *reinterpret_cast<const bf16x8*>(&P_lds[w][lr][lg * 8]);

        // ---- O += P V ----
        #pragma unroll
        for (int dt = 0; dt < 4; ++dt)
            o[dt] = __builtin_amdgcn_mfma_f32_16x16x32_bf16(pa, vf[dt], o[dt], 0, 0, 0);
    }

    // ---- epilogue: normalize by row sum, store fp32 ----
    #pragma unroll
    for (int r = 0; r < 4; ++r) {
        const float inv = 1.0f / l_r[r];
        const int qg = q0 + w * 16 + lg * 4 + r;
        #pragma unroll
        for (int dt = 0; dt < 4; ++dt)
            Ob[(size_t)qg * DH + dt * 16 + lr] = o[dt][r] * inv;
    }
}

extern "C" void kernel_launch(void* const* d_in, const int* in_sizes, int n_in,
                              void* d_out, int out_size, void* d_ws, size_t ws_size,
                              hipStream_t stream) {
    const float* Q = (const float*)d_in[0];
    const float* K = (const float*)d_in[1];
    const float* V = (const float*)d_in[2];
    // d_in[3] is the causal mask — synthesized in-kernel, not read.
    float* O = (float*)d_out;

    const int BH = 64;                       // B*H
    dim3 grid(BH * (SEQ / QBLK));            // 2048 blocks
    attn_fwd<<<grid, 256, 0, stream>>>(Q, K, V, O);
}

// Round 2
// 299.593 us; speedup vs baseline: 2.0145x; 2.0145x over previous
//
#include <hip/hip_runtime.h>

#define SEQ  2048
#define DH   64
#define QBLK 64          // q rows per block = 4 waves x 16
#define KBLK 64          // k/v rows per staged tile
#define NQB  (SEQ/QBLK)

typedef short bf16x8 __attribute__((ext_vector_type(8)));   // 8 bf16 bits = 4 VGPRs
typedef float f32x4  __attribute__((ext_vector_type(4)));

// fp32 -> bf16 bits, round-to-nearest-even
__device__ __forceinline__ short bfbits(float f) {
    unsigned int u = __float_as_uint(f);
    u += 0x7fff + ((u >> 16) & 1);
    return (short)(u >> 16);
}

// swizzled short-index into a [rows][64] bf16 LDS tile (row stride 128 B).
// XOR on bits 3..5 of the element index == bits 4..6 of the byte address:
// spreads the 128B-stride column across 8 distinct 16B slots (2-way = free).
__device__ __forceinline__ int swz(int row, int col) {
    return row * 64 + (col ^ ((row & 7) << 3));
}

__global__ __launch_bounds__(256) void attn_fwd(const float* __restrict__ Qg,
                                                const float* __restrict__ Kg,
                                                const float* __restrict__ Vg,
                                                float* __restrict__ Og) {
    __shared__ __align__(16) short Ks[64 * 64];      // K tile  [k][d], swizzled
    __shared__ __align__(16) short Vt[64 * 64];      // V tile  [d][k], swizzled
    __shared__ __align__(16) short Ps[4 * 16 * 64];  // per-wave P [q][k], swizzled

    const int tid  = threadIdx.x;
    const int w    = tid >> 6;
    const int lane = tid & 63;
    const int lg   = lane >> 4;
    const int lr   = lane & 15;

    const int qblk = blockIdx.x & (NQB - 1);
    const int bh   = blockIdx.x / NQB;
    const int q0   = qblk * QBLK;

    const float* Qb = Qg + (size_t)bh * SEQ * DH;
    const float* Kb = Kg + (size_t)bh * SEQ * DH;
    const float* Vb = Vg + (size_t)bh * SEQ * DH;
    float*       Ob = Og + (size_t)bh * SEQ * DH;

    // ---- Q fragments (A-layout: row=lane&15, k-chunk=(lane>>4)*8), 1/8 scale folded ----
    bf16x8 qf[2];
    {
        const float* qp = Qb + (size_t)(q0 + w * 16 + lr) * DH + lg * 8;
        #pragma unroll
        for (int c = 0; c < 2; ++c) {
            const float4 a = *reinterpret_cast<const float4*>(qp + c * 32);
            const float4 b = *reinterpret_cast<const float4*>(qp + c * 32 + 4);
            bf16x8 r;
            r[0] = bfbits(a.x * 0.125f); r[1] = bfbits(a.y * 0.125f);
            r[2] = bfbits(a.z * 0.125f); r[3] = bfbits(a.w * 0.125f);
            r[4] = bfbits(b.x * 0.125f); r[5] = bfbits(b.y * 0.125f);
            r[6] = bfbits(b.z * 0.125f); r[7] = bfbits(b.w * 0.125f);
            qf[c] = r;
        }
    }

    f32x4 o[4];
    #pragma unroll
    for (int dt = 0; dt < 4; ++dt) o[dt] = (f32x4){0.f, 0.f, 0.f, 0.f};
    float m_r[4], l_r[4];
    #pragma unroll
    for (int r = 0; r < 4; ++r) { m_r[r] = -1e30f; l_r[r] = 0.f; }

    // staging thread mapping
    const int skr  = tid >> 2;          // K: row within tile
    const int sd0  = (tid & 3) * 16;    // K: col group (16 f32)
    const int svk  = tid & 63;          // V: k row within tile
    const int svd0 = (tid >> 6) * 16;   // V: d group (16 f32)

    const int kend   = q0 + w * 16 + 16;  // wave's causal k limit
    const int kb_max = q0 + QBLK;

    for (int kb = 0; kb < kb_max; kb += KBLK) {
        __syncthreads();   // previous tile's consumers done

        // ---- stage K tile: coalesced row loads -> swizzled b128 writes ----
        {
            const float* src = Kb + (size_t)(kb + skr) * DH + sd0;
            const float4 a0 = *reinterpret_cast<const float4*>(src);
            const float4 a1 = *reinterpret_cast<const float4*>(src + 4);
            const float4 a2 = *reinterpret_cast<const float4*>(src + 8);
            const float4 a3 = *reinterpret_cast<const float4*>(src + 12);
            bf16x8 h0, h1;
            h0[0]=bfbits(a0.x); h0[1]=bfbits(a0.y); h0[2]=bfbits(a0.z); h0[3]=bfbits(a0.w);
            h0[4]=bfbits(a1.x); h0[5]=bfbits(a1.y); h0[6]=bfbits(a1.z); h0[7]=bfbits(a1.w);
            h1[0]=bfbits(a2.x); h1[1]=bfbits(a2.y); h1[2]=bfbits(a2.z); h1[3]=bfbits(a2.w);
            h1[4]=bfbits(a3.x); h1[5]=bfbits(a3.y); h1[6]=bfbits(a3.z); h1[7]=bfbits(a3.w);
            *reinterpret_cast<bf16x8*>(&Ks[swz(skr, sd0)])     = h0;
            *reinterpret_cast<bf16x8*>(&Ks[swz(skr, sd0 + 8)]) = h1;
        }
        // ---- stage V transposed: row loads -> u16 scatter (row-uniform per write => conflict-free) ----
        {
            const float* src = Vb + (size_t)(kb + svk) * DH + svd0;
            const float4 b0 = *reinterpret_cast<const float4*>(src);
            const float4 b1 = *reinterpret_cast<const float4*>(src + 4);
            const float4 b2 = *reinterpret_cast<const float4*>(src + 8);
            const float4 b3 = *reinterpret_cast<const float4*>(src + 12);
            const float vv[16] = {b0.x,b0.y,b0.z,b0.w, b1.x,b1.y,b1.z,b1.w,
                                  b2.x,b2.y,b2.z,b2.w, b3.x,b3.y,b3.z,b3.w};
            #pragma unroll
            for (int i = 0; i < 16; ++i)
                Vt[swz(svd0 + i, svk)] = bfbits(vv[i]);
        }
        __syncthreads();

        if (kb < kend) {   // wave-uniform causal skip
            // ---- K fragments from LDS ----
            bf16x8 kf[4][2];
            #pragma unroll
            for (int kt = 0; kt < 4; ++kt)
                #pragma unroll
                for (int c = 0; c < 2; ++c)
                    kf[kt][c] = *reinterpret_cast<const bf16x8*>(&Ks[swz(kt * 16 + lr, c * 32 + lg * 8)]);

            // ---- S = Q K^T : four 16x16 column tiles ----
            f32x4 s[4];
            #pragma unroll
            for (int kt = 0; kt < 4; ++kt) {
                s[kt] = (f32x4){0.f, 0.f, 0.f, 0.f};
                s[kt] = __builtin_amdgcn_mfma_f32_16x16x32_bf16(qf[0], kf[kt][0], s[kt], 0, 0, 0);
                s[kt] = __builtin_amdgcn_mfma_f32_16x16x32_bf16(qf[1], kf[kt][1], s[kt], 0, 0, 0);
            }

            // ---- causal mask: only boundary tiles ----
            #pragma unroll
            for (int kt = 0; kt < 4; ++kt) {
                const int c0 = kb + kt * 16;
                if (c0 + 15 > q0 + w * 16) {
                    #pragma unroll
                    for (int r = 0; r < 4; ++r)
                        if (c0 + lr > q0 + w * 16 + lg * 4 + r) s[kt][r] = -1e30f;
                }
            }

            // ---- row max: in-lane across 4 tiles, then 16-lane shfl tree ----
            float mx[4];
            #pragma unroll
            for (int r = 0; r < 4; ++r)
                mx[r] = fmaxf(fmaxf(s[0][r], s[1][r]), fmaxf(s[2][r], s[3][r]));
            #pragma unroll
            for (int d = 1; d < 16; d <<= 1)
                #pragma unroll
                for (int r = 0; r < 4; ++r)
                    mx[r] = fmaxf(mx[r], __shfl_xor(mx[r], d));

            // ---- online softmax update ----
            float scl[4];
            #pragma unroll
            for (int r = 0; r < 4; ++r) {
                const float mn = fmaxf(m_r[r], mx[r]);
                scl[r] = __expf(m_r[r] - mn);
                m_r[r] = mn;
            }
            float p[4][4], sm[4];
            #pragma unroll
            for (int r = 0; r < 4; ++r) sm[r] = 0.f;
            #pragma unroll
            for (int kt = 0; kt < 4; ++kt)
                #pragma unroll
                for (int r = 0; r < 4; ++r) {
                    p[kt][r] = __expf(s[kt][r] - m_r[r]);
                    sm[r] += p[kt][r];
                }
            #pragma unroll
            for (int d = 1; d < 16; d <<= 1)
                #pragma unroll
                for (int r = 0; r < 4; ++r)
                    sm[r] += __shfl_xor(sm[r], d);
            #pragma unroll
            for (int r = 0; r < 4; ++r)
                l_r[r] = l_r[r] * scl[r] + sm[r];
            #pragma unroll
            for (int dt = 0; dt < 4; ++dt)
                #pragma unroll
                for (int r = 0; r < 4; ++r)
                    o[dt][r] *= scl[r];

            // ---- P: D-layout -> swizzled LDS (wave-private, no barrier needed) ----
            const int pb = w * 1024;
            #pragma unroll
            for (int kt = 0; kt < 4; ++kt)
                #pragma unroll
                for (int r = 0; r < 4; ++r)
                    Ps[pb + swz(lg * 4 + r, kt * 16 + lr)] = bfbits(p[kt][r]);

            // ---- V fragments (B-layout from transposed tile) ----
            bf16x8 vf[4][2];
            #pragma unroll
            for (int dt = 0; dt < 4; ++dt)
                #pragma unroll
                for (int ks = 0; ks < 2; ++ks)
                    vf[dt][ks] = *reinterpret_cast<const bf16x8*>(&Vt[swz(dt * 16 + lr, ks * 32 + lg * 8)]);

            // ---- P fragments (A-layout) ----
            bf16x8 pa[2];
            #pragma unroll
            for (int ks = 0; ks < 2; ++ks)
                pa[ks] = *reinterpret_cast<const bf16x8*>(&Ps[pb + swz(lr, ks * 32 + lg * 8)]);

            // ---- O += P V ----
            #pragma unroll
            for (int dt = 0; dt < 4; ++dt) {
                o[dt] = __builtin_amdgcn_mfma_f32_16x16x32_bf16(pa[0], vf[dt][0], o[dt], 0, 0, 0);
                o[dt] = __builtin_amdgcn_mfma_f32_16x16x32_bf16(pa[1], vf[dt][1], o[dt], 0, 0, 0);
            }
        }
    }

    // ---- epilogue ----
    #pragma unroll
    for (int r = 0; r < 4; ++r) {
        const float inv = 1.0f / l_r[r];
        const int qg = q0 + w * 16 + lg * 4 + r;
        #pragma unroll
        for (int dt = 0; dt < 4; ++dt)
            Ob[(size_t)qg * DH + dt * 16 + lr] = o[dt][r] * inv;
    }
}

extern "C" void kernel_launch(void* const* d_in, const int* in_sizes, int n_in,
                              void* d_out, int out_size, void* d_ws, size_t ws_size,
                              hipStream_t stream) {
    const float* Q = (const float*)d_in[0];
    const float* K = (const float*)d_in[1];
    const float* V = (const float*)d_in[2];
    // d_in[3] causal mask: synthesized in-kernel, not read.
    float* O = (float*)d_out;

    dim3 grid(64 * NQB);   // (B*H) * (S/QBLK) = 2048 blocks
    attn_fwd<<<grid, 256, 0, stream>>>(Q, K, V, O);
}

// Round 3
// 210.592 us; speedup vs baseline: 2.8659x; 1.4226x over previous
//
#include <hip/hip_runtime.h>

#define SEQ  2048
#define DH   64
#define QBLK 128         // q rows per block = 4 waves x 2 subtiles x 16
#define KBLK 64          // k/v rows per staged tile
#define NQB  (SEQ/QBLK)  // 16
#define THR  11.5f       // defer-max threshold, log2 domain (~e^8)

typedef short bf16x8 __attribute__((ext_vector_type(8)));   // 8 bf16 bits = 4 VGPRs
typedef float f32x4  __attribute__((ext_vector_type(4)));

// fp32 -> bf16 bits, round-to-nearest-even
__device__ __forceinline__ short bfbits(float f) {
    unsigned int u = __float_as_uint(f);
    u += 0x7fff + ((u >> 16) & 1);
    return (short)(u >> 16);
}

// swizzled short-index into a [rows][64] bf16 LDS tile (row stride 128 B):
// XOR bits 3..5 of elem idx (bits 4..6 of byte addr) with row bits 0..2.
__device__ __forceinline__ int swz(int row, int col) {
    return row * 64 + (col ^ ((row & 7) << 3));
}

__global__ __launch_bounds__(256) void attn_fwd(const float* __restrict__ Qg,
                                                const float* __restrict__ Kg,
                                                const float* __restrict__ Vg,
                                                float* __restrict__ Og) {
    __shared__ __align__(16) short Ks[64 * 64];      // K tile [k][d], swizzled
    __shared__ __align__(16) short Vt[64 * 64];      // V tile [d][k], swizzled
    __shared__ __align__(16) short Ps[4 * 16 * 64];  // per-wave P [q][k], swizzled

    const int tid  = threadIdx.x;
    const int w    = tid >> 6;
    const int lane = tid & 63;
    const int lg   = lane >> 4;
    const int lr   = lane & 15;

    const int qblk = blockIdx.x & (NQB - 1);
    const int bh   = blockIdx.x / NQB;
    const int q0   = qblk * QBLK;

    const float* Qb = Qg + (size_t)bh * SEQ * DH;
    const float* Kb = Kg + (size_t)bh * SEQ * DH;
    const float* Vb = Vg + (size_t)bh * SEQ * DH;
    float*       Ob = Og + (size_t)bh * SEQ * DH;

    // 1/sqrt(64) * log2(e): exp2-direct softmax
    const float SC = 0.125f * 1.44269504f;

    // ---- Q fragments for both subtiles (A-layout: row=lane&15, chunk=(lane>>4)*8) ----
    bf16x8 qf[2][2];
    #pragma unroll
    for (int sub = 0; sub < 2; ++sub) {
        const float* qp = Qb + (size_t)(q0 + sub * 64 + w * 16 + lr) * DH + lg * 8;
        #pragma unroll
        for (int c = 0; c < 2; ++c) {
            const float4 a = *reinterpret_cast<const float4*>(qp + c * 32);
            const float4 b = *reinterpret_cast<const float4*>(qp + c * 32 + 4);
            bf16x8 r;
            r[0] = bfbits(a.x * SC); r[1] = bfbits(a.y * SC);
            r[2] = bfbits(a.z * SC); r[3] = bfbits(a.w * SC);
            r[4] = bfbits(b.x * SC); r[5] = bfbits(b.y * SC);
            r[6] = bfbits(b.z * SC); r[7] = bfbits(b.w * SC);
            qf[sub][c] = r;
        }
    }

    f32x4 o[2][4];
    float m_r[2][4], l_r[2][4];
    #pragma unroll
    for (int sub = 0; sub < 2; ++sub) {
        #pragma unroll
        for (int dt = 0; dt < 4; ++dt) o[sub][dt] = (f32x4){0.f, 0.f, 0.f, 0.f};
        #pragma unroll
        for (int r = 0; r < 4; ++r) { m_r[sub][r] = -1e30f; l_r[sub][r] = 0.f; }
    }

    // staging thread mapping
    const int skr  = tid >> 2;          // K: row in tile
    const int sd0  = (tid & 3) * 16;    // K: 16-f32 col group
    const int svk  = tid & 63;          // V: k row
    const int svd0 = (tid >> 6) * 16;   // V: 16-f32 d group

    const int kend0 = q0 + w * 16 + 16;       // subtile 0 causal limit
    const int kend1 = q0 + 64 + w * 16 + 16;  // subtile 1 causal limit
    const int kb_max = q0 + QBLK;

    for (int kb = 0; kb < kb_max; kb += KBLK) {
        __syncthreads();
        // ---- stage K tile ----
        {
            const float* src = Kb + (size_t)(kb + skr) * DH + sd0;
            const float4 a0 = *reinterpret_cast<const float4*>(src);
            const float4 a1 = *reinterpret_cast<const float4*>(src + 4);
            const float4 a2 = *reinterpret_cast<const float4*>(src + 8);
            const float4 a3 = *reinterpret_cast<const float4*>(src + 12);
            bf16x8 h0, h1;
            h0[0]=bfbits(a0.x); h0[1]=bfbits(a0.y); h0[2]=bfbits(a0.z); h0[3]=bfbits(a0.w);
            h0[4]=bfbits(a1.x); h0[5]=bfbits(a1.y); h0[6]=bfbits(a1.z); h0[7]=bfbits(a1.w);
            h1[0]=bfbits(a2.x); h1[1]=bfbits(a2.y); h1[2]=bfbits(a2.z); h1[3]=bfbits(a2.w);
            h1[4]=bfbits(a3.x); h1[5]=bfbits(a3.y); h1[6]=bfbits(a3.z); h1[7]=bfbits(a3.w);
            *reinterpret_cast<bf16x8*>(&Ks[swz(skr, sd0)])     = h0;
            *reinterpret_cast<bf16x8*>(&Ks[swz(skr, sd0 + 8)]) = h1;
        }
        // ---- stage V transposed ----
        {
            const float* src = Vb + (size_t)(kb + svk) * DH + svd0;
            const float4 b0 = *reinterpret_cast<const float4*>(src);
            const float4 b1 = *reinterpret_cast<const float4*>(src + 4);
            const float4 b2 = *reinterpret_cast<const float4*>(src + 8);
            const float4 b3 = *reinterpret_cast<const float4*>(src + 12);
            const float vv[16] = {b0.x,b0.y,b0.z,b0.w, b1.x,b1.y,b1.z,b1.w,
                                  b2.x,b2.y,b2.z,b2.w, b3.x,b3.y,b3.z,b3.w};
            #pragma unroll
            for (int i = 0; i < 16; ++i)
                Vt[swz(svd0 + i, svk)] = bfbits(vv[i]);
        }
        __syncthreads();

        // K fragments shared by both subtiles (held in regs)
        bf16x8 kf[4][2];
        if (kb < kend1) {
            #pragma unroll
            for (int kt = 0; kt < 4; ++kt)
                #pragma unroll
                for (int c = 0; c < 2; ++c)
                    kf[kt][c] = *reinterpret_cast<const bf16x8*>(&Ks[swz(kt * 16 + lr, c * 32 + lg * 8)]);
        }

        #pragma unroll
        for (int sub = 0; sub < 2; ++sub) {
            const int kend = sub ? kend1 : kend0;
            if (kb < kend) {
                const int qbase = q0 + sub * 64 + w * 16;

                // ---- S = Q K^T ----
                f32x4 s[4];
                #pragma unroll
                for (int kt = 0; kt < 4; ++kt) {
                    s[kt] = (f32x4){0.f, 0.f, 0.f, 0.f};
                    s[kt] = __builtin_amdgcn_mfma_f32_16x16x32_bf16(qf[sub][0], kf[kt][0], s[kt], 0, 0, 0);
                    s[kt] = __builtin_amdgcn_mfma_f32_16x16x32_bf16(qf[sub][1], kf[kt][1], s[kt], 0, 0, 0);
                }

                // ---- causal mask (boundary tiles only) ----
                #pragma unroll
                for (int kt = 0; kt < 4; ++kt) {
                    const int c0 = kb + kt * 16;
                    if (c0 + 15 > qbase) {
                        #pragma unroll
                        for (int r = 0; r < 4; ++r)
                            if (c0 + lr > qbase + lg * 4 + r) s[kt][r] = -1e30f;
                    }
                }

                // ---- in-lane max + defer-max fast path ----
                float mxl[4];
                int fastok = 1;
                #pragma unroll
                for (int r = 0; r < 4; ++r) {
                    mxl[r] = fmaxf(fmaxf(s[0][r], s[1][r]), fmaxf(s[2][r], s[3][r]));
                    fastok &= (mxl[r] <= m_r[sub][r] + THR);
                }
                if (!__all(fastok)) {       // slow path: true row max + rescale
                    #pragma unroll
                    for (int d = 1; d < 16; d <<= 1)
                        #pragma unroll
                        for (int r = 0; r < 4; ++r)
                            mxl[r] = fmaxf(mxl[r], __shfl_xor(mxl[r], d));
                    float scl[4];
                    #pragma unroll
                    for (int r = 0; r < 4; ++r) {
                        const float mn = fmaxf(m_r[sub][r], mxl[r]);
                        scl[r] = __builtin_amdgcn_exp2f(m_r[sub][r] - mn);
                        m_r[sub][r] = mn;
                        l_r[sub][r] *= scl[r];
                    }
                    #pragma unroll
                    for (int dt = 0; dt < 4; ++dt)
                        #pragma unroll
                        for (int r = 0; r < 4; ++r)
                            o[sub][dt][r] *= scl[r];
                }

                // ---- P = exp2(S - m), lane-partial row sum (no shuffle) ----
                float p[4][4];
                #pragma unroll
                for (int kt = 0; kt < 4; ++kt)
                    #pragma unroll
                    for (int r = 0; r < 4; ++r)
                        p[kt][r] = __builtin_amdgcn_exp2f(s[kt][r] - m_r[sub][r]);
                #pragma unroll
                for (int r = 0; r < 4; ++r)
                    l_r[sub][r] += (p[0][r] + p[1][r]) + (p[2][r] + p[3][r]);

                // ---- P -> swizzled LDS (wave-private) ----
                const int pb = w * 1024;
                #pragma unroll
                for (int kt = 0; kt < 4; ++kt)
                    #pragma unroll
                    for (int r = 0; r < 4; ++r)
                        Ps[pb + swz(lg * 4 + r, kt * 16 + lr)] = bfbits(p[kt][r]);

                // ---- V and P fragments ----
                bf16x8 vf[4][2];
                #pragma unroll
                for (int dt = 0; dt < 4; ++dt)
                    #pragma unroll
                    for (int ks = 0; ks < 2; ++ks)
                        vf[dt][ks] = *reinterpret_cast<const bf16x8*>(&Vt[swz(dt * 16 + lr, ks * 32 + lg * 8)]);
                bf16x8 pa[2];
                #pragma unroll
                for (int ks = 0; ks < 2; ++ks)
                    pa[ks] = *reinterpret_cast<const bf16x8*>(&Ps[pb + swz(lr, ks * 32 + lg * 8)]);

                // ---- O += P V ----
                #pragma unroll
                for (int dt = 0; dt < 4; ++dt) {
                    o[sub][dt] = __builtin_amdgcn_mfma_f32_16x16x32_bf16(pa[0], vf[dt][0], o[sub][dt], 0, 0, 0);
                    o[sub][dt] = __builtin_amdgcn_mfma_f32_16x16x32_bf16(pa[1], vf[dt][1], o[sub][dt], 0, 0, 0);
                }
            }
        }
    }

    // ---- epilogue: reduce lane-partial l across the 16 lanes of each row, store ----
    #pragma unroll
    for (int sub = 0; sub < 2; ++sub) {
        #pragma unroll
        for (int d = 1; d < 16; d <<= 1)
            #pragma unroll
            for (int r = 0; r < 4; ++r)
                l_r[sub][r] += __shfl_xor(l_r[sub][r], d);
        #pragma unroll
        for (int r = 0; r < 4; ++r) {
            const float inv = 1.0f / l_r[sub][r];
            const int qg = q0 + sub * 64 + w * 16 + lg * 4 + r;
            #pragma unroll
            for (int dt = 0; dt < 4; ++dt)
                Ob[(size_t)qg * DH + dt * 16 + lr] = o[sub][dt][r] * inv;
        }
    }
}

extern "C" void kernel_launch(void* const* d_in, const int* in_sizes, int n_in,
                              void* d_out, int out_size, void* d_ws, size_t ws_size,
                              hipStream_t stream) {
    const float* Q = (const float*)d_in[0];
    const float* K = (const float*)d_in[1];
    const float* V = (const float*)d_in[2];
    // d_in[3] causal mask: synthesized in-kernel, not read.
    float* O = (float*)d_out;

    dim3 grid(64 * NQB);   // (B*H) * (S/QBLK) = 1024 blocks
    attn_fwd<<<grid, 256, 0, stream>>>(Q, K, V, O);
}